// Round 11
// baseline (638.879 us; speedup 1.0000x reference)
//
#include <hip/hip_runtime.h>
#include <math.h>

// ws layout (in floats). stat region doubles as statp0 (K-half 0 partial).
// Setup scratch (statp1/ypart/ystat) overlays loop scratch (dynp/hw/sumc):
// setup strictly precedes loop in stream order.
#define OFF_PHI    0u
#define SZ_PHI     (64u*1024u)
#define OFF_CS     (OFF_PHI + SZ_PHI)          // 65,536
#define SZ_CS      (64u*2048u)
#define OFF_STAT   (OFF_CS + SZ_CS)            // 196,608 (also statp0)
#define SZ_STAT    (3u*1024u*512u)
#define OFF_SCR    (OFF_STAT + SZ_STAT)        // 1,769,472
// setup view of scratch
#define OFF_STATP1 OFF_SCR                     // 1,572,864 floats
#define OFF_YPART  (OFF_STATP1 + SZ_STAT)      // 196,608 floats
#define OFF_YSTAT  (OFF_YPART + 3u*8u*16u*512u)  // 24,576 floats
// loop view of scratch (overlays the above)
#define OFF_DYNP   OFF_SCR                     // 48*64*512 = 1,572,864
#define OFF_HW     (OFF_DYNP + 48u*64u*512u)
#define OFF_SUMC   (OFF_HW + 64u*512u)

#define OUT_S_FLOATS (64u*11u*1024u*2u)        // 1441792

// ---------------------------------------------------------------------------
// ypart[mlp][slab][m][h] = sum_{k in slab(256)} y[k][m] * W1[(4096+k)*512+h]
__global__ __launch_bounds__(512) void k_ystat_part(
    const float* __restrict__ y,
    const float* __restrict__ eW1, const float* __restrict__ rW1,
    const float* __restrict__ mW1, float* __restrict__ ypart) {
  int mlp = blockIdx.x, m = blockIdx.y, slab = blockIdx.z, h = threadIdx.x;
  const float* W1 = (mlp == 0) ? eW1 : (mlp == 1) ? rW1 : mW1;
  int k0 = slab * 256;
  const float* Wp = W1 + (size_t)(4096 + k0) * 512 + h;
  const float* yp = y + (size_t)k0 * 16 + m;
  float acc = 0.f;
  #pragma unroll 8
  for (int l = 0; l < 256; ++l)
    acc = fmaf(yp[l * 16], Wp[(size_t)l * 512], acc);
  ypart[(((size_t)mlp * 8 + slab) * 16 + m) * 512 + h] = acc;
}

// ystat[mlp][m][h] = b1[h] + sum_slab ypart
__global__ __launch_bounds__(512) void k_ystat_red(
    const float* __restrict__ ypart,
    const float* __restrict__ eb1, const float* __restrict__ rb1,
    const float* __restrict__ mb1, float* __restrict__ ystat) {
  int mlp = blockIdx.x, m = blockIdx.y, h = threadIdx.x;
  const float* b1 = (mlp == 0) ? eb1 : (mlp == 1) ? rb1 : mb1;
  float acc = b1[h];
  #pragma unroll
  for (int s = 0; s < 8; ++s)
    acc += ypart[(((size_t)mlp * 8 + s) * 16 + m) * 512 + h];
  ystat[((size_t)mlp * 16 + m) * 512 + h] = acc;
}

// ---------------------------------------------------------------------------
// statp[khalf][mlp][bm][h] = sum_{k<1024} w_{re/im}[b][k][m] * W1[(2048+1024*khalf+k)*512+h]
// A staged directly from w (coalesced along m, transposed in LDS) — no AT buffer.
// 64x64 tile, 4x4 micro, BK=32, dbuf. grid (16,8,6): z = mlp*2 + khalf. 768 blocks.
__global__ __launch_bounds__(256) void k_static_gemm(
    const float* __restrict__ wre, const float* __restrict__ wim,
    const float* __restrict__ eW1, const float* __restrict__ rW1,
    const float* __restrict__ mW1,
    float* __restrict__ statp0, float* __restrict__ statp1) {
  int mlp = blockIdx.z >> 1, khalf = blockIdx.z & 1;
  const float* W1 = (mlp == 0) ? eW1 : (mlp == 1) ? rW1 : mW1;
  const float* src = khalf ? wim : wre;
  int m0 = blockIdx.x * 64, n0 = blockIdx.y * 64;
  int b0 = m0 >> 4;                       // 4 batches per block
  const float* Bbase = W1 + (size_t)(2048 + 1024 * khalf) * 512 + n0;

  __shared__ float As[2][32][68];         // [k][bm] (+pad)
  __shared__ float Bs[2][32][64];         // [k][n]
  int tid = threadIdx.x;
  int ty = tid >> 4, tx = tid & 15;       // micro: rows 4ty.., cols 4tx..

  int a_ab0 = tid >> 7, a_al = (tid >> 2) & 31, a_am4 = (tid & 3) << 2;
  int b_br = tid >> 4, b_bn4 = (tid & 15) << 2;

  const float* ApG0 = src + ((size_t)(b0 + a_ab0)     * 1024 + a_al) * 16 + a_am4;
  const float* ApG1 = src + ((size_t)(b0 + a_ab0 + 2) * 1024 + a_al) * 16 + a_am4;
  const float* BpG0 = Bbase + (size_t)b_br * 512 + b_bn4;
  const float* BpG1 = Bbase + (size_t)(b_br + 16) * 512 + b_bn4;
  float4 a0 = *(const float4*)(ApG0);
  float4 a1 = *(const float4*)(ApG1);
  float4 bv0 = *(const float4*)(BpG0);
  float4 bv1 = *(const float4*)(BpG1);

  float acc[4][4] = {};
  int buf = 0;
  for (int kk = 0; kk < 1024; kk += 32) {
    *(float4*)&As[buf][a_al][(a_ab0 << 4) + a_am4] = a0;
    *(float4*)&As[buf][a_al][((a_ab0 + 2) << 4) + a_am4] = a1;
    *(float4*)&Bs[buf][b_br][b_bn4] = bv0;
    *(float4*)&Bs[buf][b_br + 16][b_bn4] = bv1;
    __syncthreads();
    int kn = (kk + 32 < 1024) ? kk + 32 : kk;
    a0 = *(const float4*)(ApG0 + (size_t)kn * 16);
    a1 = *(const float4*)(ApG1 + (size_t)kn * 16);
    bv0 = *(const float4*)(BpG0 + (size_t)kn * 512);
    bv1 = *(const float4*)(BpG1 + (size_t)kn * 512);
    #pragma unroll
    for (int k = 0; k < 32; ++k) {
      float4 a = *(const float4*)&As[buf][k][ty << 2];
      float4 bb = *(const float4*)&Bs[buf][k][tx << 2];
      float ar[4] = {a.x, a.y, a.z, a.w};
      float br[4] = {bb.x, bb.y, bb.z, bb.w};
      #pragma unroll
      for (int i = 0; i < 4; ++i)
        #pragma unroll
        for (int j = 0; j < 4; ++j)
          acc[i][j] = fmaf(ar[i], br[j], acc[i][j]);
    }
    buf ^= 1;
  }
  float* statp = khalf ? statp1 : statp0;
  #pragma unroll
  for (int i = 0; i < 4; ++i) {
    int bm = m0 + (ty << 2) + i;
    float* cp = statp + ((size_t)mlp * 1024 + bm) * 512 + n0 + (tx << 2);
    #pragma unroll
    for (int j = 0; j < 4; ++j) cp[j] = acc[i][j];
  }
}

// ---------------------------------------------------------------------------
// stat = statp0 + statp1 + ystat[mlp][bm&15][:]  (in-place into statp0)
__global__ __launch_bounds__(256) void k_stat_red(
    float* __restrict__ statp0, const float* __restrict__ statp1,
    const float* __restrict__ ystat) {
  unsigned f4 = blockIdx.x * 256 + threadIdx.x;
  size_t flat = (size_t)f4 * 4;
  unsigned mlp = flat >> 19;
  unsigned rem = flat & ((1u << 19) - 1);
  unsigned bm = rem >> 9, h = rem & 511;
  float4 v0 = *(const float4*)(statp0 + flat);
  float4 v1 = *(const float4*)(statp1 + flat);
  float4 ys = *(const float4*)(ystat + ((size_t)mlp * 16 + (bm & 15)) * 512 + h);
  v0.x += v1.x + ys.x; v0.y += v1.y + ys.y;
  v0.z += v1.z + ys.z; v0.w += v1.w + ys.w;
  *(float4*)(statp0 + flat) = v0;
}

// ---------------------------------------------------------------------------
// dyn partials: C[(kslab*3+mlp)*64 + r][n] = sum_{k in slab(128)} cs[r][k]*W1[k][n]
// grid (8 ntile, 16 kslab, 3 mlp) = 384 blocks
__global__ __launch_bounds__(256) void k_dyn(
    const float* __restrict__ A,
    const float* __restrict__ B0, const float* __restrict__ B1,
    const float* __restrict__ B2, float* __restrict__ C) {
  const float* Bm = (blockIdx.z == 0) ? B0 : (blockIdx.z == 1) ? B1 : B2;
  int n0 = blockIdx.x * 64;
  int kbase = blockIdx.y * 128;
  __shared__ float As[2][16][68];
  __shared__ float Bs[2][16][64];
  int tid = threadIdx.x;
  int ty = tid >> 4, tx = tid & 15;
  int arow = tid >> 2, akk = (tid & 3) << 2;
  int bkk = tid >> 4, bnn = (tid & 15) << 2;
  const float* Ap = A + (size_t)arow * 2048 + kbase + akk;
  const float* Bp = Bm + ((size_t)(kbase + bkk)) * 512 + n0 + bnn;
  float4 av = *(const float4*)(Ap);
  float4 bv = *(const float4*)(Bp);
  float acc[4][4] = {};
  int buf = 0;
  for (int k0 = 0; k0 < 128; k0 += 16) {
    As[buf][akk + 0][arow] = av.x; As[buf][akk + 1][arow] = av.y;
    As[buf][akk + 2][arow] = av.z; As[buf][akk + 3][arow] = av.w;
    *(float4*)&Bs[buf][bkk][bnn] = bv;
    __syncthreads();
    int kn = (k0 + 16 < 128) ? k0 + 16 : k0;
    av = *(const float4*)(Ap + kn);
    bv = *(const float4*)(Bp + (size_t)kn * 512);
    #pragma unroll
    for (int k = 0; k < 16; ++k) {
      float4 a = *(const float4*)&As[buf][k][ty << 2];
      float4 bb = *(const float4*)&Bs[buf][k][tx << 2];
      float ar[4] = {a.x, a.y, a.z, a.w};
      float br[4] = {bb.x, bb.y, bb.z, bb.w};
      #pragma unroll
      for (int i = 0; i < 4; ++i)
        #pragma unroll
        for (int j = 0; j < 4; ++j)
          acc[i][j] = fmaf(ar[i], br[j], acc[i][j]);
    }
    buf ^= 1;
  }
  int chunk = blockIdx.y * 3 + blockIdx.z;
  float* Cp = C + ((size_t)chunk * 64) * 512 + n0;
  #pragma unroll
  for (int i = 0; i < 4; ++i)
    #pragma unroll
    for (int j = 0; j < 4; ++j)
      Cp[((size_t)((ty << 2) + i)) * 512 + (tx << 2) + j] = acc[i][j];
}

// ---------------------------------------------------------------------------
// reduce: h_x = relu(dyn_x + stat_x); rho/mu dots; hw = sum_m coeff*h_e; sumc
// grid 64 (b), block 512 (h) — two barriers
__global__ __launch_bounds__(512) void k_reduce(
    const float* __restrict__ dynp, const float* __restrict__ stat,
    const float* __restrict__ rW2, const float* __restrict__ rb2,
    const float* __restrict__ mW2, const float* __restrict__ mb2,
    float* __restrict__ hw, float* __restrict__ sumc) {
  int b = blockIdx.x, h = threadIdx.x;
  float de = 0.f, dr = 0.f, dm = 0.f;
  #pragma unroll
  for (int s = 0; s < 16; ++s) {
    de += dynp[((size_t)((s * 3 + 0) * 64 + b)) * 512 + h];
    dr += dynp[((size_t)((s * 3 + 1) * 64 + b)) * 512 + h];
    dm += dynp[((size_t)((s * 3 + 2) * 64 + b)) * 512 + h];
  }
  float wr2 = rW2[h], wm2 = mW2[h];
  int lane = h & 63, wave = h >> 6;
  __shared__ float s_r[16][8], s_m[16][8], s_c[16];
  const float* se_p = stat + ((size_t)(0 * 1024) + b * 16) * 512 + h;
  const float* sr_p = stat + ((size_t)(1 * 1024) + b * 16) * 512 + h;
  const float* sm_p = stat + ((size_t)(2 * 1024) + b * 16) * 512 + h;
  float he[16];
  #pragma unroll
  for (int m = 0; m < 16; ++m) {
    he[m] = fmaxf(de + se_p[(size_t)m * 512], 0.f);
    float hr = fmaxf(dr + sr_p[(size_t)m * 512], 0.f);
    float hm = fmaxf(dm + sm_p[(size_t)m * 512], 0.f);
    float pr = hr * wr2, pm = hm * wm2;
    #pragma unroll
    for (int off = 32; off; off >>= 1) {
      pr += __shfl_down(pr, off);
      pm += __shfl_down(pm, off);
    }
    if (lane == 0) { s_r[m][wave] = pr; s_m[m][wave] = pm; }
  }
  __syncthreads();
  if (h < 16) {
    int m = h;
    float rho = rb2[0], mu = mb2[0];
    #pragma unroll
    for (int w = 0; w < 8; ++w) { rho += s_r[m][w]; mu += s_m[m][w]; }
    float coeff = rho * mu;
    s_c[m] = coeff;
    float t = coeff;
    #pragma unroll
    for (int off = 8; off; off >>= 1) t += __shfl_down(t, off);
    if (m == 0) sumc[b] = t;
  }
  __syncthreads();
  float hwacc = 0.f;
  #pragma unroll
  for (int m = 0; m < 16; ++m) hwacc = fmaf(s_c[m], he[m], hwacc);
  hw[(size_t)b * 512 + h] = hwacc;
}

// ---------------------------------------------------------------------------
// fused eta+update: eta[b][k] = sum_h hw[b][h]*eW2[h][k] + sumc[b]*eb2[k];
// phi -= eta; write cs + out slot t+1.  grid (4 ntile, 64 b), block 256.
// eW2 streamed from L2 (2 MB, resident); hw[b] staged in LDS.
__global__ __launch_bounds__(256) void k_eta_update(
    const float* __restrict__ hw, const float* __restrict__ eW2,
    const float* __restrict__ eb2, const float* __restrict__ sumc,
    float* __restrict__ phi, float* __restrict__ cs,
    float* __restrict__ out, int t) {
  int b = blockIdx.y;
  int kg = blockIdx.x * 256 + threadIdx.x;
  __shared__ float hws[512];
  hws[threadIdx.x] = hw[(size_t)b * 512 + threadIdx.x];
  hws[threadIdx.x + 256] = hw[(size_t)b * 512 + 256 + threadIdx.x];
  __syncthreads();
  const float* W = eW2 + kg;
  float a0 = 0.f, a1 = 0.f, a2 = 0.f, a3 = 0.f;
  #pragma unroll 4
  for (int h = 0; h < 512; h += 4) {
    a0 = fmaf(hws[h + 0], W[(size_t)(h + 0) * 1024], a0);
    a1 = fmaf(hws[h + 1], W[(size_t)(h + 1) * 1024], a1);
    a2 = fmaf(hws[h + 2], W[(size_t)(h + 2) * 1024], a2);
    a3 = fmaf(hws[h + 3], W[(size_t)(h + 3) * 1024], a3);
  }
  float e = ((a0 + a1) + (a2 + a3)) + sumc[b] * eb2[kg];
  float p = phi[(size_t)b * 1024 + kg] - e;
  phi[(size_t)b * 1024 + kg] = p;
  float sn, cn;
  sincosf(p, &sn, &cn);
  cs[(size_t)b * 2048 + kg] = cn;
  cs[(size_t)b * 2048 + 1024 + kg] = sn;
  size_t o = (((size_t)(b * 11 + t + 1)) * 1024 + kg) * 2;
  out[o] = cn; out[o + 1] = sn;
}

// ---------------------------------------------------------------------------
// init: phi = phi0; cs = [cos|sin]; out slot 0; zero mu_stack
__global__ __launch_bounds__(256) void k_init(
    const float* __restrict__ phi0, float* __restrict__ phi,
    float* __restrict__ cs, float* __restrict__ out) {
  int bid = blockIdx.x;
  if (bid < 256) {
    int i = bid * 256 + threadIdx.x;
    float p = phi0[i];
    phi[i] = p;
    int b = i >> 10, k = i & 1023;
    float sn, cn;
    sincosf(p, &sn, &cn);
    cs[(size_t)b * 2048 + k] = cn;
    cs[(size_t)b * 2048 + 1024 + k] = sn;
    size_t o = (((size_t)b * 11) * 1024 + k) * 2;
    out[o] = cn; out[o + 1] = sn;
  } else {
    int j = (bid - 256) * 256 + threadIdx.x;
    out[OUT_S_FLOATS + j] = 0.f;
  }
}

// ---------------------------------------------------------------------------
extern "C" void kernel_launch(void* const* d_in, const int* in_sizes, int n_in,
                              void* d_out, int out_size, void* d_ws, size_t ws_size,
                              hipStream_t stream) {
  const float* phi0 = (const float*)d_in[0];
  const float* wre  = (const float*)d_in[1];
  const float* wim  = (const float*)d_in[2];
  const float* y    = (const float*)d_in[3];
  const float* eW1  = (const float*)d_in[4];
  const float* eb1  = (const float*)d_in[5];
  const float* eW2  = (const float*)d_in[6];
  const float* eb2  = (const float*)d_in[7];
  const float* rW1  = (const float*)d_in[8];
  const float* rb1  = (const float*)d_in[9];
  const float* rW2  = (const float*)d_in[10];
  const float* rb2  = (const float*)d_in[11];
  const float* mW1  = (const float*)d_in[12];
  const float* mb1  = (const float*)d_in[13];
  const float* mW2  = (const float*)d_in[14];
  const float* mb2  = (const float*)d_in[15];

  float* ws     = (float*)d_ws;
  float* phi    = ws + OFF_PHI;
  float* cs     = ws + OFF_CS;
  float* stat   = ws + OFF_STAT;    // doubles as statp0
  float* statp1 = ws + OFF_STATP1;  // setup scratch
  float* ypart  = ws + OFF_YPART;   // setup scratch
  float* ystat  = ws + OFF_YSTAT;   // setup scratch
  float* dynp   = ws + OFF_DYNP;    // loop scratch (overlays setup)
  float* hw     = ws + OFF_HW;
  float* sumc   = ws + OFF_SUMC;
  float* out    = (float*)d_out;

  // Precompute
  k_ystat_part<<<dim3(3, 16, 8), dim3(512), 0, stream>>>(y, eW1, rW1, mW1, ypart);
  k_ystat_red<<<dim3(3, 16), dim3(512), 0, stream>>>(ypart, eb1, rb1, mb1, ystat);
  k_static_gemm<<<dim3(16, 8, 6), dim3(256), 0, stream>>>(
      wre, wim, eW1, rW1, mW1, stat, statp1);
  k_stat_red<<<dim3(1536), dim3(256), 0, stream>>>(stat, statp1, ystat);
  k_init<<<dim3(296), dim3(256), 0, stream>>>(phi0, phi, cs, out);

  // Unrolled recursion — 3 dispatches/step
  for (int t = 0; t < 10; ++t) {
    k_dyn<<<dim3(8, 16, 3), dim3(256), 0, stream>>>(cs, eW1, rW1, mW1, dynp);
    k_reduce<<<dim3(64), dim3(512), 0, stream>>>(
        dynp, stat, rW2, rb2, mW2, mb2, hw, sumc);
    k_eta_update<<<dim3(4, 64), dim3(256), 0, stream>>>(
        hw, eW2, eb2, sumc, phi, cs, out, t);
  }
}

// Round 12
// 595.488 us; speedup vs baseline: 1.0729x; 1.0729x over previous
//
#include <hip/hip_runtime.h>
#include <math.h>

// ws layout (in floats). stat region doubles as statp0 (K-half 0 partial).
// Setup scratch (statp1/ypart/ystat) overlays loop scratch (dynp/hw/sumc):
// setup strictly precedes loop in stream order.
#define OFF_PHI    0u
#define SZ_PHI     (64u*1024u)
#define OFF_CS     (OFF_PHI + SZ_PHI)          // 65,536
#define SZ_CS      (64u*2048u)
#define OFF_STAT   (OFF_CS + SZ_CS)            // 196,608 (also statp0)
#define SZ_STAT    (3u*1024u*512u)
#define OFF_SCR    (OFF_STAT + SZ_STAT)        // 1,769,472
// setup view of scratch
#define OFF_STATP1 OFF_SCR                     // 1,572,864 floats
#define OFF_YPART  (OFF_STATP1 + SZ_STAT)      // 196,608 floats
#define OFF_YSTAT  (OFF_YPART + 3u*8u*16u*512u)  // 24,576 floats
// loop view of scratch (overlays the above)
#define OFF_DYNP   OFF_SCR                     // 48*64*512 = 1,572,864
#define OFF_HW     (OFF_DYNP + 48u*64u*512u)
#define OFF_SUMC   (OFF_HW + 64u*512u)

#define OUT_S_FLOATS (64u*11u*1024u*2u)        // 1441792

// ---------------------------------------------------------------------------
// ypart[mlp][slab][m][h] = sum_{k in slab(256)} y[k][m] * W1[(4096+k)*512+h]
__global__ __launch_bounds__(512) void k_ystat_part(
    const float* __restrict__ y,
    const float* __restrict__ eW1, const float* __restrict__ rW1,
    const float* __restrict__ mW1, float* __restrict__ ypart) {
  int mlp = blockIdx.x, m = blockIdx.y, slab = blockIdx.z, h = threadIdx.x;
  const float* W1 = (mlp == 0) ? eW1 : (mlp == 1) ? rW1 : mW1;
  int k0 = slab * 256;
  const float* Wp = W1 + (size_t)(4096 + k0) * 512 + h;
  const float* yp = y + (size_t)k0 * 16 + m;
  float acc = 0.f;
  #pragma unroll 8
  for (int l = 0; l < 256; ++l)
    acc = fmaf(yp[l * 16], Wp[(size_t)l * 512], acc);
  ypart[(((size_t)mlp * 8 + slab) * 16 + m) * 512 + h] = acc;
}

// ystat[mlp][m][h] = b1[h] + sum_slab ypart
__global__ __launch_bounds__(512) void k_ystat_red(
    const float* __restrict__ ypart,
    const float* __restrict__ eb1, const float* __restrict__ rb1,
    const float* __restrict__ mb1, float* __restrict__ ystat) {
  int mlp = blockIdx.x, m = blockIdx.y, h = threadIdx.x;
  const float* b1 = (mlp == 0) ? eb1 : (mlp == 1) ? rb1 : mb1;
  float acc = b1[h];
  #pragma unroll
  for (int s = 0; s < 8; ++s)
    acc += ypart[(((size_t)mlp * 8 + s) * 16 + m) * 512 + h];
  ystat[((size_t)mlp * 16 + m) * 512 + h] = acc;
}

// ---------------------------------------------------------------------------
// statp[khalf][mlp][bm][h] = sum_{k<1024} w_{re/im}[b][k][m] * W1[(2048+1024*khalf+k)*512+h]
// A staged directly from w (coalesced along m, transposed in LDS) — no AT buffer.
// 64x64 tile, 4x4 micro, BK=32, dbuf. grid (16,8,6): z = mlp*2 + khalf. 768 blocks.
__global__ __launch_bounds__(256) void k_static_gemm(
    const float* __restrict__ wre, const float* __restrict__ wim,
    const float* __restrict__ eW1, const float* __restrict__ rW1,
    const float* __restrict__ mW1,
    float* __restrict__ statp0, float* __restrict__ statp1) {
  int mlp = blockIdx.z >> 1, khalf = blockIdx.z & 1;
  const float* W1 = (mlp == 0) ? eW1 : (mlp == 1) ? rW1 : mW1;
  const float* src = khalf ? wim : wre;
  int m0 = blockIdx.x * 64, n0 = blockIdx.y * 64;
  int b0 = m0 >> 4;                       // 4 batches per block
  const float* Bbase = W1 + (size_t)(2048 + 1024 * khalf) * 512 + n0;

  __shared__ float As[2][32][68];         // [k][bm] (+pad)
  __shared__ float Bs[2][32][64];         // [k][n]
  int tid = threadIdx.x;
  int ty = tid >> 4, tx = tid & 15;       // micro: rows 4ty.., cols 4tx..

  int a_ab0 = tid >> 7, a_al = (tid >> 2) & 31, a_am4 = (tid & 3) << 2;
  int b_br = tid >> 4, b_bn4 = (tid & 15) << 2;

  const float* ApG0 = src + ((size_t)(b0 + a_ab0)     * 1024 + a_al) * 16 + a_am4;
  const float* ApG1 = src + ((size_t)(b0 + a_ab0 + 2) * 1024 + a_al) * 16 + a_am4;
  const float* BpG0 = Bbase + (size_t)b_br * 512 + b_bn4;
  const float* BpG1 = Bbase + (size_t)(b_br + 16) * 512 + b_bn4;
  float4 a0 = *(const float4*)(ApG0);
  float4 a1 = *(const float4*)(ApG1);
  float4 bv0 = *(const float4*)(BpG0);
  float4 bv1 = *(const float4*)(BpG1);

  float acc[4][4] = {};
  int buf = 0;
  for (int kk = 0; kk < 1024; kk += 32) {
    *(float4*)&As[buf][a_al][(a_ab0 << 4) + a_am4] = a0;
    *(float4*)&As[buf][a_al][((a_ab0 + 2) << 4) + a_am4] = a1;
    *(float4*)&Bs[buf][b_br][b_bn4] = bv0;
    *(float4*)&Bs[buf][b_br + 16][b_bn4] = bv1;
    __syncthreads();
    int kn = (kk + 32 < 1024) ? kk + 32 : kk;
    a0 = *(const float4*)(ApG0 + (size_t)kn * 16);
    a1 = *(const float4*)(ApG1 + (size_t)kn * 16);
    bv0 = *(const float4*)(BpG0 + (size_t)kn * 512);
    bv1 = *(const float4*)(BpG1 + (size_t)kn * 512);
    #pragma unroll
    for (int k = 0; k < 32; ++k) {
      float4 a = *(const float4*)&As[buf][k][ty << 2];
      float4 bb = *(const float4*)&Bs[buf][k][tx << 2];
      float ar[4] = {a.x, a.y, a.z, a.w};
      float br[4] = {bb.x, bb.y, bb.z, bb.w};
      #pragma unroll
      for (int i = 0; i < 4; ++i)
        #pragma unroll
        for (int j = 0; j < 4; ++j)
          acc[i][j] = fmaf(ar[i], br[j], acc[i][j]);
    }
    buf ^= 1;
  }
  float* statp = khalf ? statp1 : statp0;
  #pragma unroll
  for (int i = 0; i < 4; ++i) {
    int bm = m0 + (ty << 2) + i;
    float* cp = statp + ((size_t)mlp * 1024 + bm) * 512 + n0 + (tx << 2);
    #pragma unroll
    for (int j = 0; j < 4; ++j) cp[j] = acc[i][j];
  }
}

// ---------------------------------------------------------------------------
// stat = statp0 + statp1 + ystat[mlp][bm&15][:]  (in-place into statp0)
__global__ __launch_bounds__(256) void k_stat_red(
    float* __restrict__ statp0, const float* __restrict__ statp1,
    const float* __restrict__ ystat) {
  unsigned f4 = blockIdx.x * 256 + threadIdx.x;
  size_t flat = (size_t)f4 * 4;
  unsigned mlp = flat >> 19;
  unsigned rem = flat & ((1u << 19) - 1);
  unsigned bm = rem >> 9, h = rem & 511;
  float4 v0 = *(const float4*)(statp0 + flat);
  float4 v1 = *(const float4*)(statp1 + flat);
  float4 ys = *(const float4*)(ystat + ((size_t)mlp * 16 + (bm & 15)) * 512 + h);
  v0.x += v1.x + ys.x; v0.y += v1.y + ys.y;
  v0.z += v1.z + ys.z; v0.w += v1.w + ys.w;
  *(float4*)(statp0 + flat) = v0;
}

// ---------------------------------------------------------------------------
// dyn partials: C[(kslab*3+mlp)*64 + r][n] = sum_{k in slab(128)} cs[r][k]*W1[k][n]
// grid (8 ntile, 16 kslab, 3 mlp) = 384 blocks
__global__ __launch_bounds__(256) void k_dyn(
    const float* __restrict__ A,
    const float* __restrict__ B0, const float* __restrict__ B1,
    const float* __restrict__ B2, float* __restrict__ C) {
  const float* Bm = (blockIdx.z == 0) ? B0 : (blockIdx.z == 1) ? B1 : B2;
  int n0 = blockIdx.x * 64;
  int kbase = blockIdx.y * 128;
  __shared__ float As[2][16][68];
  __shared__ float Bs[2][16][64];
  int tid = threadIdx.x;
  int ty = tid >> 4, tx = tid & 15;
  int arow = tid >> 2, akk = (tid & 3) << 2;
  int bkk = tid >> 4, bnn = (tid & 15) << 2;
  const float* Ap = A + (size_t)arow * 2048 + kbase + akk;
  const float* Bp = Bm + ((size_t)(kbase + bkk)) * 512 + n0 + bnn;
  float4 av = *(const float4*)(Ap);
  float4 bv = *(const float4*)(Bp);
  float acc[4][4] = {};
  int buf = 0;
  for (int k0 = 0; k0 < 128; k0 += 16) {
    As[buf][akk + 0][arow] = av.x; As[buf][akk + 1][arow] = av.y;
    As[buf][akk + 2][arow] = av.z; As[buf][akk + 3][arow] = av.w;
    *(float4*)&Bs[buf][bkk][bnn] = bv;
    __syncthreads();
    int kn = (k0 + 16 < 128) ? k0 + 16 : k0;
    av = *(const float4*)(Ap + kn);
    bv = *(const float4*)(Bp + (size_t)kn * 512);
    #pragma unroll
    for (int k = 0; k < 16; ++k) {
      float4 a = *(const float4*)&As[buf][k][ty << 2];
      float4 bb = *(const float4*)&Bs[buf][k][tx << 2];
      float ar[4] = {a.x, a.y, a.z, a.w};
      float br[4] = {bb.x, bb.y, bb.z, bb.w};
      #pragma unroll
      for (int i = 0; i < 4; ++i)
        #pragma unroll
        for (int j = 0; j < 4; ++j)
          acc[i][j] = fmaf(ar[i], br[j], acc[i][j]);
    }
    buf ^= 1;
  }
  int chunk = blockIdx.y * 3 + blockIdx.z;
  float* Cp = C + ((size_t)chunk * 64) * 512 + n0;
  #pragma unroll
  for (int i = 0; i < 4; ++i)
    #pragma unroll
    for (int j = 0; j < 4; ++j)
      Cp[((size_t)((ty << 2) + i)) * 512 + (tx << 2) + j] = acc[i][j];
}

// ---------------------------------------------------------------------------
// reduce: h_x = relu(dyn_x + stat_x); rho/mu dots; hw = sum_m coeff*h_e; sumc
// grid 64 (b), block 512 (h) — two barriers
__global__ __launch_bounds__(512) void k_reduce(
    const float* __restrict__ dynp, const float* __restrict__ stat,
    const float* __restrict__ rW2, const float* __restrict__ rb2,
    const float* __restrict__ mW2, const float* __restrict__ mb2,
    float* __restrict__ hw, float* __restrict__ sumc) {
  int b = blockIdx.x, h = threadIdx.x;
  float de = 0.f, dr = 0.f, dm = 0.f;
  #pragma unroll
  for (int s = 0; s < 16; ++s) {
    de += dynp[((size_t)((s * 3 + 0) * 64 + b)) * 512 + h];
    dr += dynp[((size_t)((s * 3 + 1) * 64 + b)) * 512 + h];
    dm += dynp[((size_t)((s * 3 + 2) * 64 + b)) * 512 + h];
  }
  float wr2 = rW2[h], wm2 = mW2[h];
  int lane = h & 63, wave = h >> 6;
  __shared__ float s_r[16][8], s_m[16][8], s_c[16];
  const float* se_p = stat + ((size_t)(0 * 1024) + b * 16) * 512 + h;
  const float* sr_p = stat + ((size_t)(1 * 1024) + b * 16) * 512 + h;
  const float* sm_p = stat + ((size_t)(2 * 1024) + b * 16) * 512 + h;
  float he[16];
  #pragma unroll
  for (int m = 0; m < 16; ++m) {
    he[m] = fmaxf(de + se_p[(size_t)m * 512], 0.f);
    float hr = fmaxf(dr + sr_p[(size_t)m * 512], 0.f);
    float hm = fmaxf(dm + sm_p[(size_t)m * 512], 0.f);
    float pr = hr * wr2, pm = hm * wm2;
    #pragma unroll
    for (int off = 32; off; off >>= 1) {
      pr += __shfl_down(pr, off);
      pm += __shfl_down(pm, off);
    }
    if (lane == 0) { s_r[m][wave] = pr; s_m[m][wave] = pm; }
  }
  __syncthreads();
  if (h < 16) {
    int m = h;
    float rho = rb2[0], mu = mb2[0];
    #pragma unroll
    for (int w = 0; w < 8; ++w) { rho += s_r[m][w]; mu += s_m[m][w]; }
    float coeff = rho * mu;
    s_c[m] = coeff;
    float t = coeff;
    #pragma unroll
    for (int off = 8; off; off >>= 1) t += __shfl_down(t, off);
    if (m == 0) sumc[b] = t;
  }
  __syncthreads();
  float hwacc = 0.f;
  #pragma unroll
  for (int m = 0; m < 16; ++m) hwacc = fmaf(s_c[m], he[m], hwacc);
  hw[(size_t)b * 512 + h] = hwacc;
}

// ---------------------------------------------------------------------------
// fused eta+update: eta[b][k] = sum_h hw[b][h]*eW2[h][k] + sumc[b]*eb2[k];
// phi -= eta; write cs + out slot t+1.  grid (4 ntile, 64 b), block 256.
// Depth-2 software-pipelined column loads (16 in flight) to cover L2 latency;
// wrap-masked prefetch addresses keep the tail branch-free.
__global__ __launch_bounds__(256) void k_eta_update(
    const float* __restrict__ hw, const float* __restrict__ eW2,
    const float* __restrict__ eb2, const float* __restrict__ sumc,
    float* __restrict__ phi, float* __restrict__ cs,
    float* __restrict__ out, int t) {
  int b = blockIdx.y;
  int kg = blockIdx.x * 256 + threadIdx.x;
  __shared__ float hws[512];
  hws[threadIdx.x] = hw[(size_t)b * 512 + threadIdx.x];
  hws[threadIdx.x + 256] = hw[(size_t)b * 512 + 256 + threadIdx.x];

  const float* W = eW2 + kg;
  float pold = phi[(size_t)b * 1024 + kg];
  float sc = sumc[b];
  float ebk = eb2[kg];

  float c0[8], c1[8];
  #pragma unroll
  for (int j = 0; j < 8; ++j) c0[j] = W[(size_t)j * 1024];
  #pragma unroll
  for (int j = 0; j < 8; ++j) c1[j] = W[(size_t)(8 + j) * 1024];

  __syncthreads();

  float a[8] = {};
  for (int h = 0; h < 512; h += 16) {
    #pragma unroll
    for (int j = 0; j < 8; ++j)
      a[j] = fmaf(hws[h + j], c0[j], a[j]);
    #pragma unroll
    for (int j = 0; j < 8; ++j)
      c0[j] = W[(size_t)((h + 16 + j) & 511) * 1024];   // wrap: dead after tail
    #pragma unroll
    for (int j = 0; j < 8; ++j)
      a[j] = fmaf(hws[h + 8 + j], c1[j], a[j]);
    #pragma unroll
    for (int j = 0; j < 8; ++j)
      c1[j] = W[(size_t)((h + 24 + j) & 511) * 1024];   // wrap: dead after tail
  }
  float e = (((a[0] + a[1]) + (a[2] + a[3])) + ((a[4] + a[5]) + (a[6] + a[7])))
            + sc * ebk;
  float p = pold - e;
  phi[(size_t)b * 1024 + kg] = p;
  float sn, cn;
  sincosf(p, &sn, &cn);
  cs[(size_t)b * 2048 + kg] = cn;
  cs[(size_t)b * 2048 + 1024 + kg] = sn;
  size_t o = (((size_t)(b * 11 + t + 1)) * 1024 + kg) * 2;
  out[o] = cn; out[o + 1] = sn;
}

// ---------------------------------------------------------------------------
// init: phi = phi0; cs = [cos|sin]; out slot 0; zero mu_stack
__global__ __launch_bounds__(256) void k_init(
    const float* __restrict__ phi0, float* __restrict__ phi,
    float* __restrict__ cs, float* __restrict__ out) {
  int bid = blockIdx.x;
  if (bid < 256) {
    int i = bid * 256 + threadIdx.x;
    float p = phi0[i];
    phi[i] = p;
    int b = i >> 10, k = i & 1023;
    float sn, cn;
    sincosf(p, &sn, &cn);
    cs[(size_t)b * 2048 + k] = cn;
    cs[(size_t)b * 2048 + 1024 + k] = sn;
    size_t o = (((size_t)b * 11) * 1024 + k) * 2;
    out[o] = cn; out[o + 1] = sn;
  } else {
    int j = (bid - 256) * 256 + threadIdx.x;
    out[OUT_S_FLOATS + j] = 0.f;
  }
}

// ---------------------------------------------------------------------------
extern "C" void kernel_launch(void* const* d_in, const int* in_sizes, int n_in,
                              void* d_out, int out_size, void* d_ws, size_t ws_size,
                              hipStream_t stream) {
  const float* phi0 = (const float*)d_in[0];
  const float* wre  = (const float*)d_in[1];
  const float* wim  = (const float*)d_in[2];
  const float* y    = (const float*)d_in[3];
  const float* eW1  = (const float*)d_in[4];
  const float* eb1  = (const float*)d_in[5];
  const float* eW2  = (const float*)d_in[6];
  const float* eb2  = (const float*)d_in[7];
  const float* rW1  = (const float*)d_in[8];
  const float* rb1  = (const float*)d_in[9];
  const float* rW2  = (const float*)d_in[10];
  const float* rb2  = (const float*)d_in[11];
  const float* mW1  = (const float*)d_in[12];
  const float* mb1  = (const float*)d_in[13];
  const float* mW2  = (const float*)d_in[14];
  const float* mb2  = (const float*)d_in[15];

  float* ws     = (float*)d_ws;
  float* phi    = ws + OFF_PHI;
  float* cs     = ws + OFF_CS;
  float* stat   = ws + OFF_STAT;    // doubles as statp0
  float* statp1 = ws + OFF_STATP1;  // setup scratch
  float* ypart  = ws + OFF_YPART;   // setup scratch
  float* ystat  = ws + OFF_YSTAT;   // setup scratch
  float* dynp   = ws + OFF_DYNP;    // loop scratch (overlays setup)
  float* hw     = ws + OFF_HW;
  float* sumc   = ws + OFF_SUMC;
  float* out    = (float*)d_out;

  // Precompute
  k_ystat_part<<<dim3(3, 16, 8), dim3(512), 0, stream>>>(y, eW1, rW1, mW1, ypart);
  k_ystat_red<<<dim3(3, 16), dim3(512), 0, stream>>>(ypart, eb1, rb1, mb1, ystat);
  k_static_gemm<<<dim3(16, 8, 6), dim3(256), 0, stream>>>(
      wre, wim, eW1, rW1, mW1, stat, statp1);
  k_stat_red<<<dim3(1536), dim3(256), 0, stream>>>(stat, statp1, ystat);
  k_init<<<dim3(296), dim3(256), 0, stream>>>(phi0, phi, cs, out);

  // Unrolled recursion — 3 dispatches/step
  for (int t = 0; t < 10; ++t) {
    k_dyn<<<dim3(8, 16, 3), dim3(256), 0, stream>>>(cs, eW1, rW1, mW1, dynp);
    k_reduce<<<dim3(64), dim3(512), 0, stream>>>(
        dynp, stat, rW2, rb2, mW2, mb2, hw, sumc);
    k_eta_update<<<dim3(4, 64), dim3(256), 0, stream>>>(
        hw, eW2, eb2, sumc, phi, cs, out, t);
  }
}

// Round 13
// 535.877 us; speedup vs baseline: 1.1922x; 1.1112x over previous
//
#include <hip/hip_runtime.h>
#include <math.h>

// ws layout (in floats). stat region doubles as statp0 (K-half 0 partial).
// Setup scratch (statp1/ypart/ystat) overlays loop scratch (dynp/hw/sumc/etap):
// setup strictly precedes loop in stream order.
#define OFF_PHI    0u
#define SZ_PHI     (64u*1024u)
#define OFF_CS     (OFF_PHI + SZ_PHI)          // 65,536
#define SZ_CS      (64u*2048u)
#define OFF_STAT   (OFF_CS + SZ_CS)            // 196,608 (also statp0)
#define SZ_STAT    (3u*1024u*512u)
#define OFF_SCR    (OFF_STAT + SZ_STAT)        // 1,769,472
// setup view of scratch
#define OFF_STATP1 OFF_SCR                     // 1,572,864 floats
#define OFF_YPART  (OFF_STATP1 + SZ_STAT)      // 196,608 floats
#define OFF_YSTAT  (OFF_YPART + 3u*8u*16u*512u)  // 24,576 floats
// loop view of scratch (overlays the above)
#define OFF_DYNP   OFF_SCR                     // 48*64*512 = 1,572,864
#define OFF_HW     (OFF_DYNP + 48u*64u*512u)
#define OFF_SUMC   (OFF_HW + 64u*512u)
#define OFF_ETAP   (OFF_SUMC + 64u)            // 8*64*1024 = 524,288
// total = 1,769,472 + 2,129,984 = 3,899,456 floats = 15.6 MB (proven in R8)

#define OUT_S_FLOATS (64u*11u*1024u*2u)        // 1441792

// ---------------------------------------------------------------------------
// ypart[mlp][slab][m][h] = sum_{k in slab(256)} y[k][m] * W1[(4096+k)*512+h]
__global__ __launch_bounds__(512) void k_ystat_part(
    const float* __restrict__ y,
    const float* __restrict__ eW1, const float* __restrict__ rW1,
    const float* __restrict__ mW1, float* __restrict__ ypart) {
  int mlp = blockIdx.x, m = blockIdx.y, slab = blockIdx.z, h = threadIdx.x;
  const float* W1 = (mlp == 0) ? eW1 : (mlp == 1) ? rW1 : mW1;
  int k0 = slab * 256;
  const float* Wp = W1 + (size_t)(4096 + k0) * 512 + h;
  const float* yp = y + (size_t)k0 * 16 + m;
  float acc = 0.f;
  #pragma unroll 8
  for (int l = 0; l < 256; ++l)
    acc = fmaf(yp[l * 16], Wp[(size_t)l * 512], acc);
  ypart[(((size_t)mlp * 8 + slab) * 16 + m) * 512 + h] = acc;
}

// ystat[mlp][m][h] = b1[h] + sum_slab ypart
__global__ __launch_bounds__(512) void k_ystat_red(
    const float* __restrict__ ypart,
    const float* __restrict__ eb1, const float* __restrict__ rb1,
    const float* __restrict__ mb1, float* __restrict__ ystat) {
  int mlp = blockIdx.x, m = blockIdx.y, h = threadIdx.x;
  const float* b1 = (mlp == 0) ? eb1 : (mlp == 1) ? rb1 : mb1;
  float acc = b1[h];
  #pragma unroll
  for (int s = 0; s < 8; ++s)
    acc += ypart[(((size_t)mlp * 8 + s) * 16 + m) * 512 + h];
  ystat[((size_t)mlp * 16 + m) * 512 + h] = acc;
}

// ---------------------------------------------------------------------------
// statp[khalf][mlp][bm][h] = sum_{k<1024} w_{re/im}[b][k][m] * W1[(2048+1024*khalf+k)*512+h]
// 64x64 tile, 4x4 micro, BK=32, dbuf. grid (16,8,6): z = mlp*2 + khalf. 768 blocks.
__global__ __launch_bounds__(256) void k_static_gemm(
    const float* __restrict__ wre, const float* __restrict__ wim,
    const float* __restrict__ eW1, const float* __restrict__ rW1,
    const float* __restrict__ mW1,
    float* __restrict__ statp0, float* __restrict__ statp1) {
  int mlp = blockIdx.z >> 1, khalf = blockIdx.z & 1;
  const float* W1 = (mlp == 0) ? eW1 : (mlp == 1) ? rW1 : mW1;
  const float* src = khalf ? wim : wre;
  int m0 = blockIdx.x * 64, n0 = blockIdx.y * 64;
  int b0 = m0 >> 4;                       // 4 batches per block
  const float* Bbase = W1 + (size_t)(2048 + 1024 * khalf) * 512 + n0;

  __shared__ float As[2][32][68];         // [k][bm] (+pad)
  __shared__ float Bs[2][32][64];         // [k][n]
  int tid = threadIdx.x;
  int ty = tid >> 4, tx = tid & 15;       // micro: rows 4ty.., cols 4tx..

  int a_ab0 = tid >> 7, a_al = (tid >> 2) & 31, a_am4 = (tid & 3) << 2;
  int b_br = tid >> 4, b_bn4 = (tid & 15) << 2;

  const float* ApG0 = src + ((size_t)(b0 + a_ab0)     * 1024 + a_al) * 16 + a_am4;
  const float* ApG1 = src + ((size_t)(b0 + a_ab0 + 2) * 1024 + a_al) * 16 + a_am4;
  const float* BpG0 = Bbase + (size_t)b_br * 512 + b_bn4;
  const float* BpG1 = Bbase + (size_t)(b_br + 16) * 512 + b_bn4;
  float4 a0 = *(const float4*)(ApG0);
  float4 a1 = *(const float4*)(ApG1);
  float4 bv0 = *(const float4*)(BpG0);
  float4 bv1 = *(const float4*)(BpG1);

  float acc[4][4] = {};
  int buf = 0;
  for (int kk = 0; kk < 1024; kk += 32) {
    *(float4*)&As[buf][a_al][(a_ab0 << 4) + a_am4] = a0;
    *(float4*)&As[buf][a_al][((a_ab0 + 2) << 4) + a_am4] = a1;
    *(float4*)&Bs[buf][b_br][b_bn4] = bv0;
    *(float4*)&Bs[buf][b_br + 16][b_bn4] = bv1;
    __syncthreads();
    int kn = (kk + 32 < 1024) ? kk + 32 : kk;
    a0 = *(const float4*)(ApG0 + (size_t)kn * 16);
    a1 = *(const float4*)(ApG1 + (size_t)kn * 16);
    bv0 = *(const float4*)(BpG0 + (size_t)kn * 512);
    bv1 = *(const float4*)(BpG1 + (size_t)kn * 512);
    #pragma unroll
    for (int k = 0; k < 32; ++k) {
      float4 a = *(const float4*)&As[buf][k][ty << 2];
      float4 bb = *(const float4*)&Bs[buf][k][tx << 2];
      float ar[4] = {a.x, a.y, a.z, a.w};
      float br[4] = {bb.x, bb.y, bb.z, bb.w};
      #pragma unroll
      for (int i = 0; i < 4; ++i)
        #pragma unroll
        for (int j = 0; j < 4; ++j)
          acc[i][j] = fmaf(ar[i], br[j], acc[i][j]);
    }
    buf ^= 1;
  }
  float* statp = khalf ? statp1 : statp0;
  #pragma unroll
  for (int i = 0; i < 4; ++i) {
    int bm = m0 + (ty << 2) + i;
    float* cp = statp + ((size_t)mlp * 1024 + bm) * 512 + n0 + (tx << 2);
    #pragma unroll
    for (int j = 0; j < 4; ++j) cp[j] = acc[i][j];
  }
}

// ---------------------------------------------------------------------------
// stat = statp0 + statp1 + ystat[mlp][bm&15][:]  (in-place into statp0)
__global__ __launch_bounds__(256) void k_stat_red(
    float* __restrict__ statp0, const float* __restrict__ statp1,
    const float* __restrict__ ystat) {
  unsigned f4 = blockIdx.x * 256 + threadIdx.x;
  size_t flat = (size_t)f4 * 4;
  unsigned mlp = flat >> 19;
  unsigned rem = flat & ((1u << 19) - 1);
  unsigned bm = rem >> 9, h = rem & 511;
  float4 v0 = *(const float4*)(statp0 + flat);
  float4 v1 = *(const float4*)(statp1 + flat);
  float4 ys = *(const float4*)(ystat + ((size_t)mlp * 16 + (bm & 15)) * 512 + h);
  v0.x += v1.x + ys.x; v0.y += v1.y + ys.y;
  v0.z += v1.z + ys.z; v0.w += v1.w + ys.w;
  *(float4*)(statp0 + flat) = v0;
}

// ---------------------------------------------------------------------------
// dyn partials: C[(kslab*3+mlp)*64 + r][n] = sum_{k in slab(128)} cs[r][k]*W1[k][n]
// grid (8 ntile, 16 kslab, 3 mlp) = 384 blocks. BK=32 (4 stages), 4x4 micro, dbuf.
__global__ __launch_bounds__(256) void k_dyn(
    const float* __restrict__ A,
    const float* __restrict__ B0, const float* __restrict__ B1,
    const float* __restrict__ B2, float* __restrict__ C) {
  const float* Bm = (blockIdx.z == 0) ? B0 : (blockIdx.z == 1) ? B1 : B2;
  int n0 = blockIdx.x * 64;
  int kbase = blockIdx.y * 128;
  __shared__ float As[2][32][68];         // [k][row] (+pad)
  __shared__ float Bs[2][32][64];
  int tid = threadIdx.x;
  int ty = tid >> 4, tx = tid & 15;
  // A staging: thread covers row=tid>>2, k-quads (tid&3) and (tid&3)+4
  int arow = tid >> 2, akq = (tid & 3) << 2;
  // B staging: rows tid>>4 and (tid>>4)+16, cols (tid&15)*4
  int bkk = tid >> 4, bnn = (tid & 15) << 2;
  const float* Ap = A + (size_t)arow * 2048 + kbase + akq;
  const float* Bp = Bm + ((size_t)(kbase + bkk)) * 512 + n0 + bnn;
  float4 av0 = *(const float4*)(Ap);
  float4 av1 = *(const float4*)(Ap + 16);
  float4 bv0 = *(const float4*)(Bp);
  float4 bv1 = *(const float4*)(Bp + (size_t)16 * 512);
  float acc[4][4] = {};
  int buf = 0;
  for (int k0 = 0; k0 < 128; k0 += 32) {
    As[buf][akq + 0][arow] = av0.x; As[buf][akq + 1][arow] = av0.y;
    As[buf][akq + 2][arow] = av0.z; As[buf][akq + 3][arow] = av0.w;
    As[buf][akq + 16][arow] = av1.x; As[buf][akq + 17][arow] = av1.y;
    As[buf][akq + 18][arow] = av1.z; As[buf][akq + 19][arow] = av1.w;
    *(float4*)&Bs[buf][bkk][bnn] = bv0;
    *(float4*)&Bs[buf][bkk + 16][bnn] = bv1;
    __syncthreads();
    int kn = (k0 + 32 < 128) ? k0 + 32 : k0;
    av0 = *(const float4*)(Ap + kn);
    av1 = *(const float4*)(Ap + kn + 16);
    bv0 = *(const float4*)(Bp + (size_t)kn * 512);
    bv1 = *(const float4*)(Bp + (size_t)(kn + 16) * 512);
    #pragma unroll
    for (int k = 0; k < 32; ++k) {
      float4 a = *(const float4*)&As[buf][k][ty << 2];
      float4 bb = *(const float4*)&Bs[buf][k][tx << 2];
      float ar[4] = {a.x, a.y, a.z, a.w};
      float br[4] = {bb.x, bb.y, bb.z, bb.w};
      #pragma unroll
      for (int i = 0; i < 4; ++i)
        #pragma unroll
        for (int j = 0; j < 4; ++j)
          acc[i][j] = fmaf(ar[i], br[j], acc[i][j]);
    }
    buf ^= 1;
  }
  int chunk = blockIdx.y * 3 + blockIdx.z;
  float* Cp = C + ((size_t)chunk * 64) * 512 + n0;
  #pragma unroll
  for (int i = 0; i < 4; ++i)
    #pragma unroll
    for (int j = 0; j < 4; ++j)
      Cp[((size_t)((ty << 2) + i)) * 512 + (tx << 2) + j] = acc[i][j];
}

// ---------------------------------------------------------------------------
// reduce: h_x = relu(dyn_x + stat_x); rho/mu dots; hw = sum_m coeff*h_e; sumc
// grid 64 (b), block 512 (h) — two barriers
__global__ __launch_bounds__(512) void k_reduce(
    const float* __restrict__ dynp, const float* __restrict__ stat,
    const float* __restrict__ rW2, const float* __restrict__ rb2,
    const float* __restrict__ mW2, const float* __restrict__ mb2,
    float* __restrict__ hw, float* __restrict__ sumc) {
  int b = blockIdx.x, h = threadIdx.x;
  float de = 0.f, dr = 0.f, dm = 0.f;
  #pragma unroll
  for (int s = 0; s < 16; ++s) {
    de += dynp[((size_t)((s * 3 + 0) * 64 + b)) * 512 + h];
    dr += dynp[((size_t)((s * 3 + 1) * 64 + b)) * 512 + h];
    dm += dynp[((size_t)((s * 3 + 2) * 64 + b)) * 512 + h];
  }
  float wr2 = rW2[h], wm2 = mW2[h];
  int lane = h & 63, wave = h >> 6;
  __shared__ float s_r[16][8], s_m[16][8], s_c[16];
  const float* se_p = stat + ((size_t)(0 * 1024) + b * 16) * 512 + h;
  const float* sr_p = stat + ((size_t)(1 * 1024) + b * 16) * 512 + h;
  const float* sm_p = stat + ((size_t)(2 * 1024) + b * 16) * 512 + h;
  float he[16];
  #pragma unroll
  for (int m = 0; m < 16; ++m) {
    he[m] = fmaxf(de + se_p[(size_t)m * 512], 0.f);
    float hr = fmaxf(dr + sr_p[(size_t)m * 512], 0.f);
    float hm = fmaxf(dm + sm_p[(size_t)m * 512], 0.f);
    float pr = hr * wr2, pm = hm * wm2;
    #pragma unroll
    for (int off = 32; off; off >>= 1) {
      pr += __shfl_down(pr, off);
      pm += __shfl_down(pm, off);
    }
    if (lane == 0) { s_r[m][wave] = pr; s_m[m][wave] = pm; }
  }
  __syncthreads();
  if (h < 16) {
    int m = h;
    float rho = rb2[0], mu = mb2[0];
    #pragma unroll
    for (int w = 0; w < 8; ++w) { rho += s_r[m][w]; mu += s_m[m][w]; }
    float coeff = rho * mu;
    s_c[m] = coeff;
    float t = coeff;
    #pragma unroll
    for (int off = 8; off; off >>= 1) t += __shfl_down(t, off);
    if (m == 0) sumc[b] = t;
  }
  __syncthreads();
  float hwacc = 0.f;
  #pragma unroll
  for (int m = 0; m < 16; ++m) hwacc = fmaf(s_c[m], he[m], hwacc);
  hw[(size_t)b * 512 + h] = hwacc;
}

// ---------------------------------------------------------------------------
// eta partials: etap[(kslab*64)+r][n] = sum_{k in slab(64)} hw[r][k]*eW2[k][n]
// grid (16 ntile, 8 kslab) = 128 blocks
__global__ __launch_bounds__(256) void k_etap(
    const float* __restrict__ hw, const float* __restrict__ eW2,
    float* __restrict__ etap) {
  int n0 = blockIdx.x * 64;
  int kbase = blockIdx.y * 64;
  __shared__ float As[2][16][68];
  __shared__ float Bs[2][16][64];
  int tid = threadIdx.x;
  int ty = tid >> 4, tx = tid & 15;
  int arow = tid >> 2, akk = (tid & 3) << 2;
  int bkk = tid >> 4, bnn = (tid & 15) << 2;
  const float* Ap = hw + (size_t)arow * 512 + kbase + akk;
  const float* Bp = eW2 + (size_t)(kbase + bkk) * 1024 + n0 + bnn;
  float4 av = *(const float4*)(Ap);
  float4 bv = *(const float4*)(Bp);
  float acc[4][4] = {};
  int buf = 0;
  for (int k0 = 0; k0 < 64; k0 += 16) {
    As[buf][akk + 0][arow] = av.x; As[buf][akk + 1][arow] = av.y;
    As[buf][akk + 2][arow] = av.z; As[buf][akk + 3][arow] = av.w;
    *(float4*)&Bs[buf][bkk][bnn] = bv;
    __syncthreads();
    int kn = (k0 + 16 < 64) ? k0 + 16 : k0;
    av = *(const float4*)(Ap + kn);
    bv = *(const float4*)(Bp + (size_t)kn * 1024);
    #pragma unroll
    for (int k = 0; k < 16; ++k) {
      float4 a = *(const float4*)&As[buf][k][ty << 2];
      float4 bb = *(const float4*)&Bs[buf][k][tx << 2];
      float ar[4] = {a.x, a.y, a.z, a.w};
      float br[4] = {bb.x, bb.y, bb.z, bb.w};
      #pragma unroll
      for (int i = 0; i < 4; ++i)
        #pragma unroll
        for (int j = 0; j < 4; ++j)
          acc[i][j] = fmaf(ar[i], br[j], acc[i][j]);
    }
    buf ^= 1;
  }
  float* Cp = etap + ((size_t)blockIdx.y * 64) * 1024 + n0;
  #pragma unroll
  for (int i = 0; i < 4; ++i)
    #pragma unroll
    for (int j = 0; j < 4; ++j)
      Cp[((size_t)((ty << 2) + i)) * 1024 + (tx << 2) + j] = acc[i][j];
}

// ---------------------------------------------------------------------------
// update: eta = sum_slab etap + sumc*eb2; phi -= eta; write cs + out slot t+1
__global__ __launch_bounds__(256) void k_update(
    const float* __restrict__ etap, const float* __restrict__ eb2,
    const float* __restrict__ sumc, float* __restrict__ phi,
    float* __restrict__ cs, float* __restrict__ out, int t) {
  int i = blockIdx.x * 256 + threadIdx.x;
  int b = i >> 10, k = i & 1023;
  float e = sumc[b] * eb2[k];
  #pragma unroll
  for (int s = 0; s < 8; ++s)
    e += etap[((size_t)(s * 64 + b)) * 1024 + k];
  float p = phi[i] - e;
  phi[i] = p;
  float sn, cn;
  sincosf(p, &sn, &cn);
  cs[(size_t)b * 2048 + k] = cn;
  cs[(size_t)b * 2048 + 1024 + k] = sn;
  size_t o = (((size_t)(b * 11 + t + 1)) * 1024 + k) * 2;
  out[o] = cn; out[o + 1] = sn;
}

// ---------------------------------------------------------------------------
// init: phi = phi0; cs = [cos|sin]; out slot 0; zero mu_stack
__global__ __launch_bounds__(256) void k_init(
    const float* __restrict__ phi0, float* __restrict__ phi,
    float* __restrict__ cs, float* __restrict__ out) {
  int bid = blockIdx.x;
  if (bid < 256) {
    int i = bid * 256 + threadIdx.x;
    float p = phi0[i];
    phi[i] = p;
    int b = i >> 10, k = i & 1023;
    float sn, cn;
    sincosf(p, &sn, &cn);
    cs[(size_t)b * 2048 + k] = cn;
    cs[(size_t)b * 2048 + 1024 + k] = sn;
    size_t o = (((size_t)b * 11) * 1024 + k) * 2;
    out[o] = cn; out[o + 1] = sn;
  } else {
    int j = (bid - 256) * 256 + threadIdx.x;
    out[OUT_S_FLOATS + j] = 0.f;
  }
}

// ---------------------------------------------------------------------------
extern "C" void kernel_launch(void* const* d_in, const int* in_sizes, int n_in,
                              void* d_out, int out_size, void* d_ws, size_t ws_size,
                              hipStream_t stream) {
  const float* phi0 = (const float*)d_in[0];
  const float* wre  = (const float*)d_in[1];
  const float* wim  = (const float*)d_in[2];
  const float* y    = (const float*)d_in[3];
  const float* eW1  = (const float*)d_in[4];
  const float* eb1  = (const float*)d_in[5];
  const float* eW2  = (const float*)d_in[6];
  const float* eb2  = (const float*)d_in[7];
  const float* rW1  = (const float*)d_in[8];
  const float* rb1  = (const float*)d_in[9];
  const float* rW2  = (const float*)d_in[10];
  const float* rb2  = (const float*)d_in[11];
  const float* mW1  = (const float*)d_in[12];
  const float* mb1  = (const float*)d_in[13];
  const float* mW2  = (const float*)d_in[14];
  const float* mb2  = (const float*)d_in[15];

  float* ws     = (float*)d_ws;
  float* phi    = ws + OFF_PHI;
  float* cs     = ws + OFF_CS;
  float* stat   = ws + OFF_STAT;    // doubles as statp0
  float* statp1 = ws + OFF_STATP1;  // setup scratch
  float* ypart  = ws + OFF_YPART;   // setup scratch
  float* ystat  = ws + OFF_YSTAT;   // setup scratch
  float* dynp   = ws + OFF_DYNP;    // loop scratch (overlays setup)
  float* hw     = ws + OFF_HW;
  float* sumc   = ws + OFF_SUMC;
  float* etap   = ws + OFF_ETAP;
  float* out    = (float*)d_out;

  // Precompute
  k_ystat_part<<<dim3(3, 16, 8), dim3(512), 0, stream>>>(y, eW1, rW1, mW1, ypart);
  k_ystat_red<<<dim3(3, 16), dim3(512), 0, stream>>>(ypart, eb1, rb1, mb1, ystat);
  k_static_gemm<<<dim3(16, 8, 6), dim3(256), 0, stream>>>(
      wre, wim, eW1, rW1, mW1, stat, statp1);
  k_stat_red<<<dim3(1536), dim3(256), 0, stream>>>(stat, statp1, ystat);
  k_init<<<dim3(296), dim3(256), 0, stream>>>(phi0, phi, cs, out);

  // Unrolled recursion — 4 dispatches/step (R8-proven structure)
  for (int t = 0; t < 10; ++t) {
    k_dyn<<<dim3(8, 16, 3), dim3(256), 0, stream>>>(cs, eW1, rW1, mW1, dynp);
    k_reduce<<<dim3(64), dim3(512), 0, stream>>>(
        dynp, stat, rW2, rb2, mW2, mb2, hw, sumc);
    k_etap<<<dim3(16, 8), dim3(256), 0, stream>>>(hw, eW2, etap);
    k_update<<<dim3(256), dim3(256), 0, stream>>>(
        etap, eb2, sumc, phi, cs, out, t);
  }
}